// Round 2
// baseline (846.191 us; speedup 1.0000x reference)
//
#include <hip/hip_runtime.h>

// ---------------- problem constants ----------------
#define B_     4
#define T_     512
#define DIN    4096
#define H_     32
#define G_     8
#define HD_    128
#define S_     4096
#define CACHE_ 3584
#define M_     2048          // B*T
#define NQKV   6144          // H*HD + 2*G*HD
#define SCALE  0.08838834764831843f  // 1/sqrt(128)
#define LOG2E  1.4426950408889634f
#define QSC    (SCALE * LOG2E)       // folded into Q at rope time -> softmax in exp2 domain

typedef __attribute__((ext_vector_type(4))) float  f32x4;
typedef __attribute__((ext_vector_type(8))) short  s16x8;   // 8 bf16 (4 VGPRs) MFMA frag
typedef __attribute__((ext_vector_type(4))) unsigned short u16x4;
typedef __attribute__((ext_vector_type(8))) unsigned short u16x8;
typedef unsigned short u16;
typedef unsigned int   u32;

__device__ __forceinline__ u16 f2bf(float f) {
  u32 u = __builtin_bit_cast(u32, f);
  return (u16)((u + 0x7fffu + ((u >> 16) & 1u)) >> 16);   // RNE
}
__device__ __forceinline__ float bf2f(u16 h) {
  return __builtin_bit_cast(float, (u32)h << 16);
}
__device__ __forceinline__ f32x4 mfma16(s16x8 a, s16x8 b, f32x4 c) {
  return __builtin_amdgcn_mfma_f32_16x16x32_bf16(a, b, c, 0, 0, 0);
}
// async global->LDS, 16B per lane; LDS dest is wave-uniform base + lane*16
__device__ __forceinline__ void gload_lds16(const void* g, void* l) {
  __builtin_amdgcn_global_load_lds((__attribute__((address_space(1))) void*)g,
                                   (__attribute__((address_space(3))) void*)l, 16, 0, 0);
}

// ---------------- phase 0: x f32 -> bf16 ----------------
__global__ __launch_bounds__(256) void k_cvt_x(const float* __restrict__ x, u16* __restrict__ xb) {
  size_t i = ((size_t)blockIdx.x * 256 + threadIdx.x) * 4;
  f32x4 v = *(const f32x4*)(x + i);
  u16x4 o = { f2bf(v[0]), f2bf(v[1]), f2bf(v[2]), f2bf(v[3]) };
  *(u16x4*)(xb + i) = o;
}

// ---------------- phase 0: weight transpose f32[K][ldn] -> bf16[ldn][4096] ----------------
__global__ __launch_bounds__(256) void k_twt(const float* __restrict__ src, int ldn,
                                             u16* __restrict__ dst) {
  __shared__ float tile[64][68];
  int k0 = blockIdx.x * 64, n0 = blockIdx.y * 64;
  int t = threadIdx.x;
  int rr = t >> 4, cc = (t & 15) * 4;
#pragma unroll
  for (int p = 0; p < 4; ++p) {
    int r = p * 16 + rr;
    f32x4 v = *(const f32x4*)(src + (size_t)(k0 + r) * ldn + n0 + cc);
    tile[r][cc] = v[0]; tile[r][cc + 1] = v[1]; tile[r][cc + 2] = v[2]; tile[r][cc + 3] = v[3];
  }
  __syncthreads();
#pragma unroll
  for (int p = 0; p < 4; ++p) {
    int n = p * 16 + rr;
    u16x4 o = { f2bf(tile[cc][n]), f2bf(tile[cc + 1][n]), f2bf(tile[cc + 2][n]), f2bf(tile[cc + 3][n]) };
    *(u16x4*)(dst + (size_t)(n0 + n) * 4096 + k0 + cc) = o;
  }
}

// ---------------- phase 0: prev_k -> k_all f32 copy + bf16 ----------------
__global__ __launch_bounds__(256) void k_prep_k(const float* __restrict__ pk,
                                                float* __restrict__ k_all, u16* __restrict__ kb) {
  int bg = blockIdx.y;
  size_t si = ((size_t)blockIdx.x * 256 + threadIdx.x) * 4;   // < 3584*128
  f32x4 v = *(const f32x4*)(pk + (size_t)bg * CACHE_ * HD_ + si);
  size_t dof = (size_t)bg * S_ * HD_ + si;
  *(f32x4*)(k_all + dof) = v;
  u16x4 o = { f2bf(v[0]), f2bf(v[1]), f2bf(v[2]), f2bf(v[3]) };
  *(u16x4*)(kb + dof) = o;
}

// ---------------- phase 0: prev_v -> v_all f32 copy + transposed bf16 v_t[bg][hd][s] ----------------
__global__ __launch_bounds__(256) void k_prep_v(const float* __restrict__ pv,
                                                float* __restrict__ v_all, u16* __restrict__ vt) {
  __shared__ float tile[64][132];
  int bg = blockIdx.y, s0 = blockIdx.x * 64;
  int t = threadIdx.x;
  const float* src = pv + ((size_t)bg * CACHE_ + s0) * HD_;
  float* dc = v_all + ((size_t)bg * S_ + s0) * HD_;
  int r8 = t >> 5, c4 = (t & 31) * 4;
#pragma unroll
  for (int p = 0; p < 8; ++p) {
    int r = p * 8 + r8;
    f32x4 v = *(const f32x4*)(src + (size_t)r * HD_ + c4);
    *(f32x4*)(dc + (size_t)r * HD_ + c4) = v;
    tile[r][c4] = v[0]; tile[r][c4 + 1] = v[1]; tile[r][c4 + 2] = v[2]; tile[r][c4 + 3] = v[3];
  }
  __syncthreads();
  int hr = t >> 4, s4 = (t & 15) * 4;
#pragma unroll
  for (int p = 0; p < 8; ++p) {
    int hd = p * 16 + hr;
    u16x4 o = { f2bf(tile[s4][hd]), f2bf(tile[s4 + 1][hd]), f2bf(tile[s4 + 2][hd]), f2bf(tile[s4 + 3][hd]) };
    *(u16x4*)(vt + ((size_t)bg * HD_ + hd) * S_ + s0 + s4) = o;
  }
}

// ---------------- GEMM: C[M][N] = A[M][K]bf16 @ Bt[N][K]bf16 (m97: 128x128xBK64, global_load_lds) ----------------
template<bool OUT_F32>
__global__ __launch_bounds__(256) void k_gemm(const u16* __restrict__ A, const u16* __restrict__ Bt,
                                              void* __restrict__ Cp, int N, int K) {
  __shared__ u16 As[128 * 64];   // linear, matches global_load_lds lane order
  __shared__ u16 Bs[128 * 64];
  const int tid = threadIdx.x;
  const int m0 = blockIdx.x * 128, n0 = blockIdx.y * 128;
  const int wave = tid >> 6, lane = tid & 63;
  const int wm = (wave >> 1) * 64, wn = (wave & 1) * 64;
  const int cl = lane & 15, kl = (lane >> 4) * 8;
  const int srow = wave * 32 + (lane >> 3);   // per-lane global row within tile
  const int scol = (lane & 7) * 8;            // per-lane k-offset (8 bf16 = 16B)
  f32x4 acc[4][4] = {};
  for (int k0 = 0; k0 < K; k0 += 64) {
    __syncthreads();   // previous tile's LDS reads complete
#pragma unroll
    for (int i = 0; i < 4; ++i) {
      gload_lds16(A  + (size_t)(m0 + srow + i * 8) * K + k0 + scol, As + (wave * 32 + i * 8) * 64);
      gload_lds16(Bt + (size_t)(n0 + srow + i * 8) * K + k0 + scol, Bs + (wave * 32 + i * 8) * 64);
    }
    __syncthreads();   // drains vmcnt (LDS-bound loads) + all waves staged
#pragma unroll
    for (int kk = 0; kk < 2; ++kk) {
      s16x8 af[4], bfr[4];
#pragma unroll
      for (int mi = 0; mi < 4; ++mi) af[mi]  = *(const s16x8*)(As + (wm + mi * 16 + cl) * 64 + kk * 32 + kl);
#pragma unroll
      for (int ni = 0; ni < 4; ++ni) bfr[ni] = *(const s16x8*)(Bs + (wn + ni * 16 + cl) * 64 + kk * 32 + kl);
#pragma unroll
      for (int mi = 0; mi < 4; ++mi)
#pragma unroll
        for (int ni = 0; ni < 4; ++ni)
          acc[mi][ni] = mfma16(af[mi], bfr[ni], acc[mi][ni]);
    }
  }
  const int rl = (lane >> 4) * 4;
#pragma unroll
  for (int mi = 0; mi < 4; ++mi)
#pragma unroll
    for (int ni = 0; ni < 4; ++ni) {
      int col = n0 + wn + ni * 16 + cl;
#pragma unroll
      for (int r = 0; r < 4; ++r) {
        int rw = m0 + wm + mi * 16 + rl + r;
        if (OUT_F32) ((float*)Cp)[(size_t)rw * N + col] = acc[mi][ni][r];
        else         ((u16*)Cp)[(size_t)rw * N + col]   = f2bf(acc[mi][ni][r]);
      }
    }
}

// ---------------- RoPE + scatter (Q pre-scaled by SCALE*log2e for exp2-domain softmax) ----------------
__global__ __launch_bounds__(256) void k_rope(const u16* __restrict__ qkv, const float* __restrict__ cosT,
                                              const float* __restrict__ sinT, const int* __restrict__ sp,
                                              u16* __restrict__ qr, u16* __restrict__ kb,
                                              float* __restrict__ k_all, float* __restrict__ v_all) {
  int bt = blockIdx.x;
  int b = bt >> 9, t = bt & 511;
  int pos = sp[b] + t;
  const u16* row = qkv + (size_t)bt * NQKV;
  for (int idx = threadIdx.x; idx < 2560; idx += 256) {   // 40 roped heads * 64 pairs
    int head = idx >> 6, d = idx & 63;
    float c = cosT[pos * HD_ + d], s = sinT[pos * HD_ + d];
    float x1 = bf2f(row[head * HD_ + d]);
    float x2 = bf2f(row[head * HD_ + d + 64]);
    float y1 = x1 * c - x2 * s;
    float y2 = x2 * c + x1 * s;
    if (head < 32) {
      size_t o = (((size_t)b * H_ + head) * T_ + t) * HD_ + d;
      qr[o] = f2bf(y1 * QSC); qr[o + 64] = f2bf(y2 * QSC);
    } else {
      int g = head - 32;
      size_t o = (((size_t)b * G_ + g) * S_ + CACHE_ + t) * HD_ + d;
      kb[o] = f2bf(y1); kb[o + 64] = f2bf(y2);
      k_all[o] = y1; k_all[o + 64] = y2;
    }
  }
  for (int idx = threadIdx.x; idx < 1024; idx += 256) {   // v passthrough (f32 copy only)
    int g = idx >> 7;
    float v = bf2f(row[5120 + idx]);
    size_t o = (((size_t)b * G_ + g) * S_ + CACHE_ + t) * HD_ + (idx & 127);
    v_all[o] = v;
  }
}

// ---------------- transpose new-V slice into v_t[bg][hd][CACHE_..S] ----------------
__global__ __launch_bounds__(256) void k_tv_new(const u16* __restrict__ qkv, u16* __restrict__ vt) {
  __shared__ u16 tile[64][72];
  int bg = blockIdx.y;
  int b = bg >> 3, g = bg & 7;
  int tt = blockIdx.x >> 1, ht = blockIdx.x & 1;
  int t0 = tt * 64, hd0 = ht * 64;
  int t = threadIdx.x;
  int rr = t >> 3, c8 = (t & 7) * 8;
#pragma unroll
  for (int p = 0; p < 2; ++p) {
    int r = p * 32 + rr;
    *(u16x8*)(&tile[r][c8]) =
      *(const u16x8*)(qkv + (size_t)(b * T_ + t0 + r) * NQKV + 5120 + g * HD_ + hd0 + c8);
  }
  __syncthreads();
  int hr = t >> 4, s4 = (t & 15) * 4;
#pragma unroll
  for (int p = 0; p < 4; ++p) {
    int hd = p * 16 + hr;
    u16x4 o = { tile[s4][hd], tile[s4 + 1][hd], tile[s4 + 2][hd], tile[s4 + 3][hd] };
    *(u16x4*)(vt + ((size_t)bg * HD_ + hd0 + hd) * S_ + CACHE_ + t0 + s4) = o;
  }
}

// ---------------- flash attention: 1 block per (qtile64, h, b); 4 waves x 16 q-rows ----------------
// LDS 34304 B -> 4 blocks/CU; P aliased into Ks; K/V reg-prefetch; exp2-domain softmax; defer-max.
__global__ __launch_bounds__(256, 4) void k_attn(const u16* __restrict__ Q, const u16* __restrict__ Kc,
                                                 const u16* __restrict__ Vt, const int* __restrict__ sp,
                                                 u16* __restrict__ ctx) {
  __shared__ u16 Ks[64 * 132];    // K tile [kv64][hd128] pad->132 (2-way max)
  __shared__ u16 Vs[128 * 68];    // V^T tile [hd128][kv64] pad->68
  u16* Pl = Ks;                   // P [64 rows][64 kv] stride 68, aliased into Ks (dead after QK)
  const int qt = blockIdx.x, h = blockIdx.y, b = blockIdx.z;
  const int g = h >> 2;           // GS = 4
  const int tid = threadIdx.x, wave = tid >> 6, lane = tid & 63;
  const int cl = lane & 15, kl = (lane >> 4) * 8, rl = (lane >> 4) * 4;
  const int cache = sp[b];
  const size_t kvoff = (size_t)(b * G_ + g) * S_ * HD_;
  const u16* kp = Kc + kvoff;
  const u16* vp = Vt + kvoff;     // v_t slab is also 128*4096 per (b,g)
  s16x8 aq[4];
  {
    const u16* qb = Q + (((size_t)(b * H_ + h)) * T_ + qt * 64 + wave * 16 + cl) * HD_;
#pragma unroll
    for (int kk = 0; kk < 4; ++kk) aq[kk] = *(const s16x8*)(qb + kk * 32 + kl);
  }
  f32x4 acc[8] = {};
  float mr[4] = { -1e30f, -1e30f, -1e30f, -1e30f };
  float ls[4] = { 0.f, 0.f, 0.f, 0.f };
  const int qi0 = qt * 64;
  const int jlast = (cache + qi0 + 63) >> 6;
  const int kr = tid >> 4, kc = (tid & 15) * 8;
  const int vr = tid >> 3, vc = (tid & 7) * 8;
  // prologue: load tile 0 into regs
  u16x8 rk[4], rv[4];
#pragma unroll
  for (int i = 0; i < 4; ++i) {
    rk[i] = *(const u16x8*)(kp + (size_t)(i * 16 + kr) * HD_ + kc);
    rv[i] = *(const u16x8*)(vp + (size_t)(i * 32 + vr) * S_ + vc);
  }
  for (int j = 0; j <= jlast; ++j) {
    __syncthreads();   // (A) all waves done reading LDS (also drains prefetch vmcnt - data needed now)
#pragma unroll
    for (int i = 0; i < 4; ++i) {
      *(u16x8*)(Ks + (i * 16 + kr) * 132 + kc) = rk[i];
      *(u16x8*)(Vs + (i * 32 + vr) * 68 + vc) = rv[i];
    }
    __syncthreads();   // (B) staging visible (no vmem outstanding here -> cheap drain)
    // prefetch next tile: flies across QK+softmax+PV, consumed at next (A)
    if (j < jlast) {
#pragma unroll
      for (int i = 0; i < 4; ++i) {
        rk[i] = *(const u16x8*)(kp + (size_t)((j + 1) * 64 + i * 16 + kr) * HD_ + kc);
        rv[i] = *(const u16x8*)(vp + (size_t)(i * 32 + vr) * S_ + (j + 1) * 64 + vc);
      }
    }
    // S = Q K^T  (16x64 per wave), exp2-domain (Q pre-scaled)
    f32x4 s4v[4] = {};
#pragma unroll
    for (int kk = 0; kk < 4; ++kk)
#pragma unroll
      for (int n = 0; n < 4; ++n) {
        s16x8 bk = *(const s16x8*)(Ks + (n * 16 + cl) * 132 + kk * 32 + kl);
        s4v[n] = mfma16(aq[kk], bk, s4v[n]);
      }
    // causal mask: only the last tile can be partial (kv_min = cache+qi0 there)
    if (j == jlast) {
#pragma unroll
      for (int n = 0; n < 4; ++n) {
        int kv = j * 64 + n * 16 + cl;
#pragma unroll
        for (int r = 0; r < 4; ++r) {
          int qi = qi0 + wave * 16 + rl + r;
          if (kv > cache + qi) s4v[n][r] = -1e30f;
        }
      }
    }
    // row max (16-lane groups)
    float pmax[4];
#pragma unroll
    for (int r = 0; r < 4; ++r) {
      float mx = fmaxf(fmaxf(s4v[0][r], s4v[1][r]), fmaxf(s4v[2][r], s4v[3][r]));
      mx = fmaxf(mx, __shfl_xor(mx, 1));
      mx = fmaxf(mx, __shfl_xor(mx, 2));
      mx = fmaxf(mx, __shfl_xor(mx, 4));
      mx = fmaxf(mx, __shfl_xor(mx, 8));
      pmax[r] = mx;
    }
    // defer-max (T13): rescale only when max grew > 8 (2^8 = 256 headroom, bf16-safe)
    int need = 0;
#pragma unroll
    for (int r = 0; r < 4; ++r) need |= (pmax[r] > mr[r] + 8.f) ? 1 : 0;
    if (__any(need)) {
#pragma unroll
      for (int r = 0; r < 4; ++r) {
        float mn = fmaxf(mr[r], pmax[r]);
        float al = __builtin_amdgcn_exp2f(mr[r] - mn);
        mr[r] = mn; ls[r] *= al;
#pragma unroll
        for (int n = 0; n < 8; ++n) acc[n][r] *= al;
      }
    }
    // (C) raw barrier: all waves' Ks reads complete before P overwrites Ks region.
    // lgkmcnt(0) drains this wave's LDS ops in HW; "memory" pins compiler ordering (rule #18).
    asm volatile("s_waitcnt lgkmcnt(0)" ::: "memory");
    __builtin_amdgcn_s_barrier();
    asm volatile("" ::: "memory");
    // exp2 + P store (round-half-up, 2 ops) + row sum
    float rsum[4] = { 0.f, 0.f, 0.f, 0.f };
#pragma unroll
    for (int n = 0; n < 4; ++n)
#pragma unroll
      for (int r = 0; r < 4; ++r) {
        float pv = __builtin_amdgcn_exp2f(s4v[n][r] - mr[r]);
        rsum[r] += pv;
        u32 u = __builtin_bit_cast(u32, pv);
        Pl[(wave * 16 + rl + r) * 68 + n * 16 + cl] = (u16)((u + 0x8000u) >> 16);
      }
#pragma unroll
    for (int r = 0; r < 4; ++r) {
      float rs = rsum[r];
      rs += __shfl_xor(rs, 1); rs += __shfl_xor(rs, 2);
      rs += __shfl_xor(rs, 4); rs += __shfl_xor(rs, 8);
      ls[r] += rs;
    }
    // O += P V   (P write->read is intra-wave; compiler orders via may-alias)
#pragma unroll
    for (int kk2 = 0; kk2 < 2; ++kk2) {
      s16x8 ap = *(const s16x8*)(Pl + (wave * 16 + cl) * 68 + kk2 * 32 + kl);
#pragma unroll
      for (int n = 0; n < 8; ++n) {
        s16x8 bv = *(const s16x8*)(Vs + (n * 16 + cl) * 68 + kk2 * 32 + kl);
        acc[n] = mfma16(ap, bv, acc[n]);
      }
    }
  }
#pragma unroll
  for (int r = 0; r < 4; ++r) {
    float inv = 1.0f / ls[r];
    int qi = qi0 + wave * 16 + rl + r;
    u16* cb = ctx + ((size_t)(b * T_ + qi)) * 4096 + h * HD_;
#pragma unroll
    for (int n = 0; n < 8; ++n) cb[n * 16 + cl] = f2bf(acc[n][r] * inv);
  }
}

// ---------------- launch ----------------
extern "C" void kernel_launch(void* const* d_in, const int* in_sizes, int n_in,
                              void* d_out, int out_size, void* d_ws, size_t ws_size,
                              hipStream_t stream) {
  const float* x      = (const float*)d_in[0];
  // d_in[1] = mask (derived analytically; unused)
  const float* cosT   = (const float*)d_in[2];
  const float* sinT   = (const float*)d_in[3];
  const int*   sp     = (const int*)d_in[4];
  const float* prev_k = (const float*)d_in[5];
  const float* prev_v = (const float*)d_in[6];
  const float* q_w    = (const float*)d_in[7];
  const float* k_w    = (const float*)d_in[8];
  const float* v_w    = (const float*)d_in[9];
  const float* o_w    = (const float*)d_in[10];

  float* out   = (float*)d_out;
  float* k_all = out + (size_t)B_ * T_ * H_ * HD_;      // +8388608
  float* v_all = k_all + (size_t)B_ * G_ * S_ * HD_;    // +16777216

  char* w = (char*)d_ws;
  u16* wt_qkv = (u16*)(w);                 // [6144][4096] bf16   50331648 B
  u16* wt_o   = (u16*)(w + 50331648);      // [4096][4096] bf16   33554432 B
  u16* x_bf   = (u16*)(w + 83886080);      // [2048][4096] bf16   16777216 B
  u16* qkv_bf = (u16*)(w + 100663296);     // [2048][6144] bf16   25165824 B
  u16* q_rope = (u16*)(w + 125829120);     // [4][32][512][128]   16777216 B
  u16* k_bf   = (u16*)(w + 142606336);     // [4][8][4096][128]   33554432 B
  u16* v_t    = (u16*)(w + 176160768);     // [4][8][128][4096]   33554432 B
  u16* ctx    = (u16*)(w + 209715200);     // [2048][4096]        16777216 B
  if (ws_size < 226492416ull) return;      // workspace too small -> bench will flag it

  k_cvt_x<<<8192, 256, 0, stream>>>(x, x_bf);
  k_twt<<<dim3(64, 64), 256, 0, stream>>>(q_w, 4096, wt_qkv);
  k_twt<<<dim3(64, 16), 256, 0, stream>>>(k_w, 1024, wt_qkv + (size_t)4096 * 4096);
  k_twt<<<dim3(64, 16), 256, 0, stream>>>(v_w, 1024, wt_qkv + (size_t)5120 * 4096);
  k_twt<<<dim3(64, 64), 256, 0, stream>>>(o_w, 4096, wt_o);
  k_prep_k<<<dim3(448, 32), 256, 0, stream>>>(prev_k, k_all, k_bf);
  k_prep_v<<<dim3(56, 32), 256, 0, stream>>>(prev_v, v_all, v_t);
  k_gemm<false><<<dim3(16, 48), 256, 0, stream>>>(x_bf, wt_qkv, qkv_bf, NQKV, 4096);
  k_rope<<<2048, 256, 0, stream>>>(qkv_bf, cosT, sinT, sp, q_rope, k_bf, k_all, v_all);
  k_tv_new<<<dim3(16, 32), 256, 0, stream>>>(qkv_bf, v_t);
  k_attn<<<dim3(8, 32, 4), 256, 0, stream>>>(q_rope, k_bf, v_t, sp, ctx);
  k_gemm<true><<<dim3(16, 32), 256, 0, stream>>>(ctx, wt_o, out, 4096, 4096);
}

// Round 3
// 591.607 us; speedup vs baseline: 1.4303x; 1.4303x over previous
//
#include <hip/hip_runtime.h>

// ---------------- problem constants ----------------
#define B_     4
#define T_     512
#define DIN    4096
#define H_     32
#define G_     8
#define HD_    128
#define S_     4096
#define CACHE_ 3584
#define M_     2048          // B*T
#define NQKV   6144          // H*HD + 2*G*HD
#define SCALE  0.08838834764831843f  // 1/sqrt(128)
#define LOG2E  1.4426950408889634f
#define QSC    (SCALE * LOG2E)       // folded into Q at rope time -> softmax in exp2 domain

typedef __attribute__((ext_vector_type(4)))  float  f32x4;
typedef __attribute__((ext_vector_type(16))) float  f32x16;
typedef __attribute__((ext_vector_type(8)))  short  s16x8;   // 8 bf16 (4 VGPRs) MFMA frag
typedef __attribute__((ext_vector_type(4)))  unsigned short u16x4;
typedef __attribute__((ext_vector_type(8)))  unsigned short u16x8;
typedef __attribute__((ext_vector_type(4)))  unsigned int   u32x4;
typedef unsigned short u16;
typedef unsigned int   u32;

__device__ __forceinline__ u16 f2bf(float f) {
  u32 u = __builtin_bit_cast(u32, f);
  return (u16)((u + 0x7fffu + ((u >> 16) & 1u)) >> 16);   // RNE
}
__device__ __forceinline__ float bf2f(u16 h) {
  return __builtin_bit_cast(float, (u32)h << 16);
}
__device__ __forceinline__ f32x4 mfma16(s16x8 a, s16x8 b, f32x4 c) {
  return __builtin_amdgcn_mfma_f32_16x16x32_bf16(a, b, c, 0, 0, 0);
}
__device__ __forceinline__ u32 pkbf(float a, float b) {   // pack 2 f32 -> 2 bf16 (RNE)
  u32 r; asm("v_cvt_pk_bf16_f32 %0, %1, %2" : "=v"(r) : "v"(a), "v"(b)); return r;
}
// async global->LDS, 16B per lane; LDS dest is wave-uniform base + lane*16
__device__ __forceinline__ void gload_lds16(const void* g, void* l) {
  __builtin_amdgcn_global_load_lds((__attribute__((address_space(1))) void*)g,
                                   (__attribute__((address_space(3))) void*)l, 16, 0, 0);
}

// ---------------- phase 0: x f32 -> bf16 ----------------
__global__ __launch_bounds__(256) void k_cvt_x(const float* __restrict__ x, u16* __restrict__ xb) {
  size_t i = ((size_t)blockIdx.x * 256 + threadIdx.x) * 4;
  f32x4 v = *(const f32x4*)(x + i);
  u16x4 o = { f2bf(v[0]), f2bf(v[1]), f2bf(v[2]), f2bf(v[3]) };
  *(u16x4*)(xb + i) = o;
}

// ---------------- phase 0: weight transpose f32[K][ldn] -> bf16[ldn][4096] ----------------
__global__ __launch_bounds__(256) void k_twt(const float* __restrict__ src, int ldn,
                                             u16* __restrict__ dst) {
  __shared__ float tile[64][68];
  int k0 = blockIdx.x * 64, n0 = blockIdx.y * 64;
  int t = threadIdx.x;
  int rr = t >> 4, cc = (t & 15) * 4;
#pragma unroll
  for (int p = 0; p < 4; ++p) {
    int r = p * 16 + rr;
    f32x4 v = *(const f32x4*)(src + (size_t)(k0 + r) * ldn + n0 + cc);
    tile[r][cc] = v[0]; tile[r][cc + 1] = v[1]; tile[r][cc + 2] = v[2]; tile[r][cc + 3] = v[3];
  }
  __syncthreads();
#pragma unroll
  for (int p = 0; p < 4; ++p) {
    int n = p * 16 + rr;
    u16x4 o = { f2bf(tile[cc][n]), f2bf(tile[cc + 1][n]), f2bf(tile[cc + 2][n]), f2bf(tile[cc + 3][n]) };
    *(u16x4*)(dst + (size_t)(n0 + n) * 4096 + k0 + cc) = o;
  }
}

// ---------------- phase 0: prev_k -> k_all f32 copy + bf16 ----------------
__global__ __launch_bounds__(256) void k_prep_k(const float* __restrict__ pk,
                                                float* __restrict__ k_all, u16* __restrict__ kb) {
  int bg = blockIdx.y;
  size_t si = ((size_t)blockIdx.x * 256 + threadIdx.x) * 4;   // < 3584*128
  f32x4 v = *(const f32x4*)(pk + (size_t)bg * CACHE_ * HD_ + si);
  size_t dof = (size_t)bg * S_ * HD_ + si;
  *(f32x4*)(k_all + dof) = v;
  u16x4 o = { f2bf(v[0]), f2bf(v[1]), f2bf(v[2]), f2bf(v[3]) };
  *(u16x4*)(kb + dof) = o;
}

// ---------------- phase 0: prev_v -> v_all f32 copy + transposed bf16 v_t[bg][hd][s] ----------------
__global__ __launch_bounds__(256) void k_prep_v(const float* __restrict__ pv,
                                                float* __restrict__ v_all, u16* __restrict__ vt) {
  __shared__ float tile[64][132];
  int bg = blockIdx.y, s0 = blockIdx.x * 64;
  int t = threadIdx.x;
  const float* src = pv + ((size_t)bg * CACHE_ + s0) * HD_;
  float* dc = v_all + ((size_t)bg * S_ + s0) * HD_;
  int r8 = t >> 5, c4 = (t & 31) * 4;
#pragma unroll
  for (int p = 0; p < 8; ++p) {
    int r = p * 8 + r8;
    f32x4 v = *(const f32x4*)(src + (size_t)r * HD_ + c4);
    *(f32x4*)(dc + (size_t)r * HD_ + c4) = v;
    tile[r][c4] = v[0]; tile[r][c4 + 1] = v[1]; tile[r][c4 + 2] = v[2]; tile[r][c4 + 3] = v[3];
  }
  __syncthreads();
  int hr = t >> 4, s4 = (t & 15) * 4;
#pragma unroll
  for (int p = 0; p < 8; ++p) {
    int hd = p * 16 + hr;
    u16x4 o = { f2bf(tile[s4][hd]), f2bf(tile[s4 + 1][hd]), f2bf(tile[s4 + 2][hd]), f2bf(tile[s4 + 3][hd]) };
    *(u16x4*)(vt + ((size_t)bg * HD_ + hd) * S_ + s0 + s4) = o;
  }
}

// ---------------- GEMM: C[M][N] = A[M][K]bf16 @ Bt[N][K]bf16 (m97: 128x128xBK64, global_load_lds) ----------------
template<bool OUT_F32>
__global__ __launch_bounds__(256) void k_gemm(const u16* __restrict__ A, const u16* __restrict__ Bt,
                                              void* __restrict__ Cp, int N, int K) {
  __shared__ u16 As[128 * 64];   // linear, matches global_load_lds lane order
  __shared__ u16 Bs[128 * 64];
  const int tid = threadIdx.x;
  const int m0 = blockIdx.x * 128, n0 = blockIdx.y * 128;
  const int wave = tid >> 6, lane = tid & 63;
  const int wm = (wave >> 1) * 64, wn = (wave & 1) * 64;
  const int cl = lane & 15, kl = (lane >> 4) * 8;
  const int srow = wave * 32 + (lane >> 3);   // per-lane global row within tile
  const int scol = (lane & 7) * 8;            // per-lane k-offset (8 bf16 = 16B)
  f32x4 acc[4][4] = {};
  for (int k0 = 0; k0 < K; k0 += 64) {
    __syncthreads();   // previous tile's LDS reads complete
#pragma unroll
    for (int i = 0; i < 4; ++i) {
      gload_lds16(A  + (size_t)(m0 + srow + i * 8) * K + k0 + scol, As + (wave * 32 + i * 8) * 64);
      gload_lds16(Bt + (size_t)(n0 + srow + i * 8) * K + k0 + scol, Bs + (wave * 32 + i * 8) * 64);
    }
    __syncthreads();   // drains vmcnt (LDS-bound loads) + all waves staged
#pragma unroll
    for (int kk = 0; kk < 2; ++kk) {
      s16x8 af[4], bfr[4];
#pragma unroll
      for (int mi = 0; mi < 4; ++mi) af[mi]  = *(const s16x8*)(As + (wm + mi * 16 + cl) * 64 + kk * 32 + kl);
#pragma unroll
      for (int ni = 0; ni < 4; ++ni) bfr[ni] = *(const s16x8*)(Bs + (wn + ni * 16 + cl) * 64 + kk * 32 + kl);
#pragma unroll
      for (int mi = 0; mi < 4; ++mi)
#pragma unroll
        for (int ni = 0; ni < 4; ++ni)
          acc[mi][ni] = mfma16(af[mi], bfr[ni], acc[mi][ni]);
    }
  }
  const int rl = (lane >> 4) * 4;
#pragma unroll
  for (int mi = 0; mi < 4; ++mi)
#pragma unroll
    for (int ni = 0; ni < 4; ++ni) {
      int col = n0 + wn + ni * 16 + cl;
#pragma unroll
      for (int r = 0; r < 4; ++r) {
        int rw = m0 + wm + mi * 16 + rl + r;
        if (OUT_F32) ((float*)Cp)[(size_t)rw * N + col] = acc[mi][ni][r];
        else         ((u16*)Cp)[(size_t)rw * N + col]   = f2bf(acc[mi][ni][r]);
      }
    }
}

// ---------------- RoPE + scatter (Q pre-scaled by SCALE*log2e for exp2-domain softmax) ----------------
__global__ __launch_bounds__(256) void k_rope(const u16* __restrict__ qkv, const float* __restrict__ cosT,
                                              const float* __restrict__ sinT, const int* __restrict__ sp,
                                              u16* __restrict__ qr, u16* __restrict__ kb,
                                              float* __restrict__ k_all, float* __restrict__ v_all) {
  int bt = blockIdx.x;
  int b = bt >> 9, t = bt & 511;
  int pos = sp[b] + t;
  const u16* row = qkv + (size_t)bt * NQKV;
  for (int idx = threadIdx.x; idx < 2560; idx += 256) {   // 40 roped heads * 64 pairs
    int head = idx >> 6, d = idx & 63;
    float c = cosT[pos * HD_ + d], s = sinT[pos * HD_ + d];
    float x1 = bf2f(row[head * HD_ + d]);
    float x2 = bf2f(row[head * HD_ + d + 64]);
    float y1 = x1 * c - x2 * s;
    float y2 = x2 * c + x1 * s;
    if (head < 32) {
      size_t o = (((size_t)b * H_ + head) * T_ + t) * HD_ + d;
      qr[o] = f2bf(y1 * QSC); qr[o + 64] = f2bf(y2 * QSC);
    } else {
      int g = head - 32;
      size_t o = (((size_t)b * G_ + g) * S_ + CACHE_ + t) * HD_ + d;
      kb[o] = f2bf(y1); kb[o + 64] = f2bf(y2);
      k_all[o] = y1; k_all[o + 64] = y2;
    }
  }
  for (int idx = threadIdx.x; idx < 1024; idx += 256) {   // v passthrough (f32 copy only)
    int g = idx >> 7;
    float v = bf2f(row[5120 + idx]);
    size_t o = (((size_t)b * G_ + g) * S_ + CACHE_ + t) * HD_ + (idx & 127);
    v_all[o] = v;
  }
}

// ---------------- transpose new-V slice into v_t[bg][hd][CACHE_..S] ----------------
__global__ __launch_bounds__(256) void k_tv_new(const u16* __restrict__ qkv, u16* __restrict__ vt) {
  __shared__ u16 tile[64][72];
  int bg = blockIdx.y;
  int b = bg >> 3, g = bg & 7;
  int tt = blockIdx.x >> 1, ht = blockIdx.x & 1;
  int t0 = tt * 64, hd0 = ht * 64;
  int t = threadIdx.x;
  int rr = t >> 3, c8 = (t & 7) * 8;
#pragma unroll
  for (int p = 0; p < 2; ++p) {
    int r = p * 32 + rr;
    *(u16x8*)(&tile[r][c8]) =
      *(const u16x8*)(qkv + (size_t)(b * T_ + t0 + r) * NQKV + 5120 + g * HD_ + hd0 + c8);
  }
  __syncthreads();
  int hr = t >> 4, s4 = (t & 15) * 4;
#pragma unroll
  for (int p = 0; p < 4; ++p) {
    int hd = p * 16 + hr;
    u16x4 o = { tile[s4][hd], tile[s4 + 1][hd], tile[s4 + 2][hd], tile[s4 + 3][hd] };
    *(u16x4*)(vt + ((size_t)bg * HD_ + hd0 + hd) * S_ + CACHE_ + t0 + s4) = o;
  }
}

// ---------------- flash attention, swapped-QK 32x32 structure ----------------
// 8 waves x 32 q-rows (block = 256 q), KV tile 64. S^T = mfma32(K, Q^T): lane owns
// q = lane&31 -> softmax in registers (no cross-lane chains except shfl_xor(32)).
// P A-frags assembled in-register (cvt_pk + shfl_xor + cndmask). K/V LDS XOR-swizzled.
__global__ __launch_bounds__(512, 2) void k_attn(const u16* __restrict__ Q, const u16* __restrict__ Kc,
                                                 const u16* __restrict__ Vt, const int* __restrict__ sp,
                                                 u16* __restrict__ ctx) {
  __shared__ u16 Ks[64 * 128];   // [kv64][128 u16], row 256B, swizzle ^((row&15)<<3) in u16 units
  __shared__ u16 Vs[128 * 64];   // [hd128][64 u16], row 128B, swizzle ^((row&7)<<3)
  const int qh = blockIdx.x, h = blockIdx.y, b = blockIdx.z;
  const int g = h >> 2;
  const int tid = threadIdx.x, w = tid >> 6, lane = tid & 63;
  const int l31 = lane & 31, hh = lane >> 5;
  const int cache = sp[b];
  const int qbase = qh * 256;
  const int qtok = qbase + w * 32 + l31;     // this lane's softmax q-row (token idx)
  const size_t kvoff = (size_t)(b * G_ + g) * S_ * HD_;
  const u16* kp = Kc + kvoff;
  const u16* vp = Vt + kvoff;
  s16x8 qreg[8];
  {
    const u16* qb = Q + ((size_t)(b * H_ + h) * T_ + qtok) * HD_;
#pragma unroll
    for (int s = 0; s < 8; ++s) qreg[s] = *(const s16x8*)(qb + s * 16 + hh * 8);
  }
  f32x16 acc[4] = {};
  float mr = -1e30f, ls = 0.f;
  const int krow = w * 8 + (lane >> 3), kch = lane & 7;   // K staging: 8 rows/wave, 2x16B per lane
  const int vrow = w * 16 + (lane >> 2), vch = lane & 3;  // V staging: 16 rows/wave, 2x16B per lane
  const int kswz = (krow & 15) << 3;
  const int vswz = (vrow & 7) << 3;
  const int rdswzK = (l31 & 15) << 3;
  const int rdswzV = (l31 & 7) << 3;
  const int jm = (cache + qbase + w * 32) >> 6;           // first tile needing mask (per wave)
  const int jlastB = (cache + qbase + 255) >> 6;          // block-uniform loop bound
  const int kvlim = cache + qtok;
  // prologue: tile 0 into regs
  u16x8 rk0 = *(const u16x8*)(kp + (size_t)krow * HD_ + kch * 8);
  u16x8 rk1 = *(const u16x8*)(kp + (size_t)krow * HD_ + (kch + 8) * 8);
  u16x8 rv0 = *(const u16x8*)(vp + (size_t)vrow * S_ + vch * 8);
  u16x8 rv1 = *(const u16x8*)(vp + (size_t)vrow * S_ + (vch + 4) * 8);
  for (int j = 0; j <= jlastB; ++j) {
    __syncthreads();   // prev tile reads done; prefetch vmcnt drains here (data needed now)
    *(u16x8*)(Ks + krow * 128 + ((kch * 8) ^ kswz))        = rk0;
    *(u16x8*)(Ks + krow * 128 + (((kch + 8) * 8) ^ kswz))  = rk1;
    *(u16x8*)(Vs + vrow * 64 + ((vch * 8) ^ vswz))         = rv0;
    *(u16x8*)(Vs + vrow * 64 + (((vch + 4) * 8) ^ vswz))   = rv1;
    __syncthreads();
    if (j < jlastB) {  // prefetch next tile; in flight across whole compute phase
      rk0 = *(const u16x8*)(kp + (size_t)((j + 1) * 64 + krow) * HD_ + kch * 8);
      rk1 = *(const u16x8*)(kp + (size_t)((j + 1) * 64 + krow) * HD_ + (kch + 8) * 8);
      rv0 = *(const u16x8*)(vp + (size_t)vrow * S_ + (j + 1) * 64 + vch * 8);
      rv1 = *(const u16x8*)(vp + (size_t)vrow * S_ + (j + 1) * 64 + vch * 8 + 32);
    }
    // S^T[kv][q] = K-tile @ Q^T  (2 kv-blocks of 32)
    f32x16 sa[2] = {};
#pragma unroll
    for (int s = 0; s < 8; ++s) {
      s16x8 ka = *(const s16x8*)(Ks + l31 * 128 + ((s * 16 + hh * 8) ^ rdswzK));
      sa[0] = __builtin_amdgcn_mfma_f32_32x32x16_bf16(ka, qreg[s], sa[0], 0, 0, 0);
    }
#pragma unroll
    for (int s = 0; s < 8; ++s) {
      s16x8 ka = *(const s16x8*)(Ks + (32 + l31) * 128 + ((s * 16 + hh * 8) ^ rdswzK));
      sa[1] = __builtin_amdgcn_mfma_f32_32x32x16_bf16(ka, qreg[s], sa[1], 0, 0, 0);
    }
    // causal mask (only tiles >= jm can have masked kv)
    if (j >= jm) {
#pragma unroll
      for (int r = 0; r < 16; ++r) {
        int kv = j * 64 + (r & 3) + 8 * (r >> 2) + 4 * hh;
        if (kv > kvlim)      sa[0][r] = -1e30f;
        if (kv + 32 > kvlim) sa[1][r] = -1e30f;
      }
    }
    // row max: in-register tree + one lane-half exchange
    float mx = sa[0][0];
#pragma unroll
    for (int r = 1; r < 16; ++r) mx = fmaxf(mx, sa[0][r]);
#pragma unroll
    for (int r = 0; r < 16; ++r) mx = fmaxf(mx, sa[1][r]);
    mx = fmaxf(mx, __shfl_xor(mx, 32));
    // defer-max (T13): rescale only when max grew > 8 (exp2 domain)
    if (__any(mx > mr + 8.f)) {
      float nm = fmaxf(mr, mx);
      float al = __builtin_amdgcn_exp2f(mr - nm);
      mr = nm; ls *= al;
#pragma unroll
      for (int r = 0; r < 16; ++r) {
        float ar = __shfl(al, (r & 3) + 8 * (r >> 2) + 4 * hh, 64);
        acc[0][r] *= ar; acc[1][r] *= ar; acc[2][r] *= ar; acc[3][r] *= ar;
      }
    }
    // exp2 + row sum (in-register)
    float rs = 0.f;
#pragma unroll
    for (int r = 0; r < 16; ++r) { sa[0][r] = __builtin_amdgcn_exp2f(sa[0][r] - mr); rs += sa[0][r]; }
#pragma unroll
    for (int r = 0; r < 16; ++r) { sa[1][r] = __builtin_amdgcn_exp2f(sa[1][r] - mr); rs += sa[1][r]; }
    rs += __shfl_xor(rs, 32);
    ls += rs;
    // pack P (D-layout) into 4 MFMA A-frags, in-register (T12 pattern)
    s16x8 pf[4];
#pragma unroll
    for (int sb = 0; sb < 2; ++sb) {
      u32 a0 = pkbf(sa[sb][0],  sa[sb][1]),  a1 = pkbf(sa[sb][2],  sa[sb][3]);
      u32 b0 = pkbf(sa[sb][4],  sa[sb][5]),  b1 = pkbf(sa[sb][6],  sa[sb][7]);
      u32 c0 = pkbf(sa[sb][8],  sa[sb][9]),  c1 = pkbf(sa[sb][10], sa[sb][11]);
      u32 d0 = pkbf(sa[sb][12], sa[sb][13]), d1 = pkbf(sa[sb][14], sa[sb][15]);
      u32 xa0 = __shfl_xor(a0, 32), xa1 = __shfl_xor(a1, 32);
      u32 xb0 = __shfl_xor(b0, 32), xb1 = __shfl_xor(b1, 32);
      u32 xc0 = __shfl_xor(c0, 32), xc1 = __shfl_xor(c1, 32);
      u32 xd0 = __shfl_xor(d0, 32), xd1 = __shfl_xor(d1, 32);
      u32x4 f0 = { hh ? xb0 : a0, hh ? xb1 : a1, hh ? b0 : xa0, hh ? b1 : xa1 };
      u32x4 f1 = { hh ? xd0 : c0, hh ? xd1 : c1, hh ? d0 : xc0, hh ? d1 : xc1 };
      pf[sb * 2]     = __builtin_bit_cast(s16x8, f0);
      pf[sb * 2 + 1] = __builtin_bit_cast(s16x8, f1);
    }
    // O += P V  (B-frags straight from swizzled Vs)
#pragma unroll
    for (int hb = 0; hb < 4; ++hb) {
      const int vro = hb * 32 + l31;
#pragma unroll
      for (int kb = 0; kb < 4; ++kb) {
        s16x8 vb = *(const s16x8*)(Vs + vro * 64 + ((kb * 16 + hh * 8) ^ rdswzV));
        acc[hb] = __builtin_amdgcn_mfma_f32_32x32x16_bf16(pf[kb], vb, acc[hb], 0, 0, 0);
      }
    }
  }
  // epilogue: normalize rows (ls lives at lane l31==row) and store ctx
  float inv = 1.0f / ls;
#pragma unroll
  for (int r = 0; r < 16; ++r) {
    int ql = (r & 3) + 8 * (r >> 2) + 4 * hh;
    float ivr = __shfl(inv, ql, 64);
    u16* cb = ctx + ((size_t)(b * T_ + qbase + w * 32 + ql)) * 4096 + h * HD_ + l31;
    cb[0]  = f2bf(acc[0][r] * ivr);
    cb[32] = f2bf(acc[1][r] * ivr);
    cb[64] = f2bf(acc[2][r] * ivr);
    cb[96] = f2bf(acc[3][r] * ivr);
  }
}

// ---------------- launch ----------------
extern "C" void kernel_launch(void* const* d_in, const int* in_sizes, int n_in,
                              void* d_out, int out_size, void* d_ws, size_t ws_size,
                              hipStream_t stream) {
  const float* x      = (const float*)d_in[0];
  // d_in[1] = mask (derived analytically; unused)
  const float* cosT   = (const float*)d_in[2];
  const float* sinT   = (const float*)d_in[3];
  const int*   sp     = (const int*)d_in[4];
  const float* prev_k = (const float*)d_in[5];
  const float* prev_v = (const float*)d_in[6];
  const float* q_w    = (const float*)d_in[7];
  const float* k_w    = (const float*)d_in[8];
  const float* v_w    = (const float*)d_in[9];
  const float* o_w    = (const float*)d_in[10];

  float* out   = (float*)d_out;
  float* k_all = out + (size_t)B_ * T_ * H_ * HD_;      // +8388608
  float* v_all = k_all + (size_t)B_ * G_ * S_ * HD_;    // +16777216

  char* w = (char*)d_ws;
  u16* wt_qkv = (u16*)(w);                 // [6144][4096] bf16   50331648 B
  u16* wt_o   = (u16*)(w + 50331648);      // [4096][4096] bf16   33554432 B
  u16* x_bf   = (u16*)(w + 83886080);      // [2048][4096] bf16   16777216 B
  u16* qkv_bf = (u16*)(w + 100663296);     // [2048][6144] bf16   25165824 B
  u16* q_rope = (u16*)(w + 125829120);     // [4][32][512][128]   16777216 B
  u16* k_bf   = (u16*)(w + 142606336);     // [4][8][4096][128]   33554432 B
  u16* v_t    = (u16*)(w + 176160768);     // [4][8][128][4096]   33554432 B
  u16* ctx    = (u16*)(w + 209715200);     // [2048][4096]        16777216 B
  if (ws_size < 226492416ull) return;      // workspace too small -> bench will flag it

  k_cvt_x<<<8192, 256, 0, stream>>>(x, x_bf);
  k_twt<<<dim3(64, 64), 256, 0, stream>>>(q_w, 4096, wt_qkv);
  k_twt<<<dim3(64, 16), 256, 0, stream>>>(k_w, 1024, wt_qkv + (size_t)4096 * 4096);
  k_twt<<<dim3(64, 16), 256, 0, stream>>>(v_w, 1024, wt_qkv + (size_t)5120 * 4096);
  k_twt<<<dim3(64, 64), 256, 0, stream>>>(o_w, 4096, wt_o);
  k_prep_k<<<dim3(448, 32), 256, 0, stream>>>(prev_k, k_all, k_bf);
  k_prep_v<<<dim3(56, 32), 256, 0, stream>>>(prev_v, v_all, v_t);
  k_gemm<false><<<dim3(16, 48), 256, 0, stream>>>(x_bf, wt_qkv, qkv_bf, NQKV, 4096);
  k_rope<<<2048, 256, 0, stream>>>(qkv_bf, cosT, sinT, sp, q_rope, k_bf, k_all, v_all);
  k_tv_new<<<dim3(16, 32), 256, 0, stream>>>(qkv_bf, v_t);
  k_attn<<<dim3(2, 32, 4), 512, 0, stream>>>(q_rope, k_bf, v_t, sp, ctx);
  k_gemm<true><<<dim3(16, 32), 256, 0, stream>>>(ctx, wt_o, out, 4096, 4096);
}

// Round 4
// 541.263 us; speedup vs baseline: 1.5634x; 1.0930x over previous
//
#include <hip/hip_runtime.h>

// ---------------- problem constants ----------------
#define B_     4
#define T_     512
#define DIN    4096
#define H_     32
#define G_     8
#define HD_    128
#define S_     4096
#define CACHE_ 3584
#define M_     2048          // B*T
#define NQKV   6144          // H*HD + 2*G*HD
#define SCALE  0.08838834764831843f  // 1/sqrt(128)
#define LOG2E  1.4426950408889634f
#define QSC    (SCALE * LOG2E)       // folded into Q at rope time -> softmax in exp2 domain

typedef __attribute__((ext_vector_type(4)))  float  f32x4;
typedef __attribute__((ext_vector_type(16))) float  f32x16;
typedef __attribute__((ext_vector_type(8)))  short  s16x8;   // 8 bf16 (4 VGPRs) MFMA frag
typedef __attribute__((ext_vector_type(4)))  unsigned short u16x4;
typedef __attribute__((ext_vector_type(8)))  unsigned short u16x8;
typedef __attribute__((ext_vector_type(4)))  unsigned int   u32x4;
typedef unsigned short u16;
typedef unsigned int   u32;

__device__ __forceinline__ u16 f2bf(float f) {
  u32 u = __builtin_bit_cast(u32, f);
  return (u16)((u + 0x7fffu + ((u >> 16) & 1u)) >> 16);   // RNE
}
__device__ __forceinline__ float bf2f(u16 h) {
  return __builtin_bit_cast(float, (u32)h << 16);
}
__device__ __forceinline__ f32x4 mfma16(s16x8 a, s16x8 b, f32x4 c) {
  return __builtin_amdgcn_mfma_f32_16x16x32_bf16(a, b, c, 0, 0, 0);
}
__device__ __forceinline__ u32 pkbf(float a, float b) {   // pack 2 f32 -> 2 bf16 (RNE)
  u32 r; asm("v_cvt_pk_bf16_f32 %0, %1, %2" : "=v"(r) : "v"(a), "v"(b)); return r;
}
// async global->LDS, 16B per lane; LDS dest is wave-uniform base + lane*16
__device__ __forceinline__ void gload_lds16(const void* g, void* l) {
  __builtin_amdgcn_global_load_lds((__attribute__((address_space(1))) void*)g,
                                   (__attribute__((address_space(3))) void*)l, 16, 0, 0);
}

// ---------------- phase 0: x f32 -> bf16 ----------------
__global__ __launch_bounds__(256) void k_cvt_x(const float* __restrict__ x, u16* __restrict__ xb) {
  size_t i = ((size_t)blockIdx.x * 256 + threadIdx.x) * 4;
  f32x4 v = *(const f32x4*)(x + i);
  u16x4 o = { f2bf(v[0]), f2bf(v[1]), f2bf(v[2]), f2bf(v[3]) };
  *(u16x4*)(xb + i) = o;
}

// ---------------- phase 0: weight transpose f32[K][ldn] -> bf16[ldn][4096] ----------------
__global__ __launch_bounds__(256) void k_twt(const float* __restrict__ src, int ldn,
                                             u16* __restrict__ dst) {
  __shared__ float tile[64][68];
  int k0 = blockIdx.x * 64, n0 = blockIdx.y * 64;
  int t = threadIdx.x;
  int rr = t >> 4, cc = (t & 15) * 4;
#pragma unroll
  for (int p = 0; p < 4; ++p) {
    int r = p * 16 + rr;
    f32x4 v = *(const f32x4*)(src + (size_t)(k0 + r) * ldn + n0 + cc);
    tile[r][cc] = v[0]; tile[r][cc + 1] = v[1]; tile[r][cc + 2] = v[2]; tile[r][cc + 3] = v[3];
  }
  __syncthreads();
#pragma unroll
  for (int p = 0; p < 4; ++p) {
    int n = p * 16 + rr;
    u16x4 o = { f2bf(tile[cc][n]), f2bf(tile[cc + 1][n]), f2bf(tile[cc + 2][n]), f2bf(tile[cc + 3][n]) };
    *(u16x4*)(dst + (size_t)(n0 + n) * 4096 + k0 + cc) = o;
  }
}

// ---------------- phase 0: prev_k -> k_all f32 copy + bf16 ----------------
__global__ __launch_bounds__(256) void k_prep_k(const float* __restrict__ pk,
                                                float* __restrict__ k_all, u16* __restrict__ kb) {
  int bg = blockIdx.y;
  size_t si = ((size_t)blockIdx.x * 256 + threadIdx.x) * 4;   // < 3584*128
  f32x4 v = *(const f32x4*)(pk + (size_t)bg * CACHE_ * HD_ + si);
  size_t dof = (size_t)bg * S_ * HD_ + si;
  *(f32x4*)(k_all + dof) = v;
  u16x4 o = { f2bf(v[0]), f2bf(v[1]), f2bf(v[2]), f2bf(v[3]) };
  *(u16x4*)(kb + dof) = o;
}

// ---------------- phase 0: prev_v -> v_all f32 copy + transposed bf16 v_t[bg][hd][s] ----------------
__global__ __launch_bounds__(256) void k_prep_v(const float* __restrict__ pv,
                                                float* __restrict__ v_all, u16* __restrict__ vt) {
  __shared__ float tile[64][132];
  int bg = blockIdx.y, s0 = blockIdx.x * 64;
  int t = threadIdx.x;
  const float* src = pv + ((size_t)bg * CACHE_ + s0) * HD_;
  float* dc = v_all + ((size_t)bg * S_ + s0) * HD_;
  int r8 = t >> 5, c4 = (t & 31) * 4;
#pragma unroll
  for (int p = 0; p < 8; ++p) {
    int r = p * 8 + r8;
    f32x4 v = *(const f32x4*)(src + (size_t)r * HD_ + c4);
    *(f32x4*)(dc + (size_t)r * HD_ + c4) = v;
    tile[r][c4] = v[0]; tile[r][c4 + 1] = v[1]; tile[r][c4 + 2] = v[2]; tile[r][c4 + 3] = v[3];
  }
  __syncthreads();
  int hr = t >> 4, s4 = (t & 15) * 4;
#pragma unroll
  for (int p = 0; p < 8; ++p) {
    int hd = p * 16 + hr;
    u16x4 o = { f2bf(tile[s4][hd]), f2bf(tile[s4 + 1][hd]), f2bf(tile[s4 + 2][hd]), f2bf(tile[s4 + 3][hd]) };
    *(u16x4*)(vt + ((size_t)bg * HD_ + hd) * S_ + s0 + s4) = o;
  }
}

// ---------------- GEMM v2: C[M][N] = A[M][K]bf16 @ Bt[N][K]bf16 ----------------
// BMx256xBK64 tile, 512 threads (8 waves 2Mx4N), dbuf LDS, global_load_lds w16
// linear-dest + inverse-swizzled SOURCE + swizzled ds_read (rule #21),
// counted vmcnt (T4), raw s_barrier + sched_barrier pins, setprio (T5),
// bijective XCD swizzle (T1, column-major tile order -> B-panel sharing).
template<int BM, bool OUT_F32>
__global__ __launch_bounds__(512, 1) void k_gemm2(const u16* __restrict__ A, const u16* __restrict__ Bt,
                                                  void* __restrict__ Cp, int M, int N, int K) {
  constexpr int MI = BM / 32;        // A-frag repeats per wave (8 or 4)
  constexpr int LA = BM / 64;        // A stage loads/thread per K-tile (4 or 2)
  __shared__ u16 As[2 * BM * 64];    // [buf][BM][64], chunk16 ch' = ch ^ (row&7)
  __shared__ u16 Bs[2 * 256 * 64];
  const int tid = threadIdx.x, w = tid >> 6, lane = tid & 63;
  const int wr = w >> 2, wc = w & 3;             // wave tile: rows wr*(BM/2), cols wc*64
  const int cl = lane & 15, khi = lane >> 4;
  // --- T1: bijective XCD swizzle, column-major (bm fast) ---
  const int Mt = M / BM;
  const int nwg = gridDim.x;
  const int q = nwg >> 3, r8 = nwg & 7;
  const int xcd = blockIdx.x & 7, pos = blockIdx.x >> 3;
  const int wgid = (xcd < r8 ? xcd * (q + 1) : r8 * (q + 1) + (xcd - r8) * q) + pos;
  const int m0 = (wgid % Mt) * BM, n0 = (wgid / Mt) * 256;
  // --- staging addresses (inverse-swizzled global source) ---
  const int rb = tid >> 3;                       // 0..63
  const int csw = ((tid & 7) ^ (rb & 7)) * 8;    // element offset, pre-swizzled
  const u16* aS = A  + (size_t)(m0 + rb) * K + csw;
  const u16* bS = Bt + (size_t)(n0 + rb) * K + csw;
  u16* aD = As + w * 512;                        // + buf*BM*64 + i*4096; lane*16B implicit
  u16* bD = Bs + w * 512;
  // --- swizzled read chunk offsets (row&7 == cl&7 for all frags) ---
  const int ck0 = ((0 + khi) ^ (cl & 7)) * 8;
  const int ck1 = ((4 + khi) ^ (cl & 7)) * 8;
  const int NT = K >> 6;
  f32x4 acc[MI][4] = {};

#define STAGE_(buf, tt)                                                                   \
  do {                                                                                    \
    _Pragma("unroll")                                                                     \
    for (int i = 0; i < LA; ++i)                                                          \
      gload_lds16(aS + (size_t)(i * 64) * K + (size_t)(tt) * 64, aD + (buf) * (BM * 64) + i * 4096); \
    _Pragma("unroll")                                                                     \
    for (int i = 0; i < 4; ++i)                                                           \
      gload_lds16(bS + (size_t)(i * 64) * K + (size_t)(tt) * 64, bD + (buf) * (256 * 64) + i * 4096); \
  } while (0)
#define VMCNT_L_()                                                                        \
  do {                                                                                    \
    if constexpr (BM == 256) asm volatile("s_waitcnt vmcnt(8)" ::: "memory");             \
    else                     asm volatile("s_waitcnt vmcnt(6)" ::: "memory");             \
  } while (0)

  STAGE_(0, 0);
  STAGE_(1, 1);
  VMCNT_L_();
  __builtin_amdgcn_sched_barrier(0);
  __builtin_amdgcn_s_barrier();
  __builtin_amdgcn_sched_barrier(0);

  for (int t = 0; t < NT; ++t) {
    const int buf = t & 1;
    const int ab = buf * (BM * 64) + (wr * (BM / 2) + cl) * 64;
    const int bb = buf * (256 * 64) + (wc * 64 + cl) * 64;
#pragma unroll
    for (int kk = 0; kk < 2; ++kk) {
      const int ck = kk ? ck1 : ck0;
      s16x8 bf4[4], af[MI];
#pragma unroll
      for (int ni = 0; ni < 4; ++ni) bf4[ni] = *(const s16x8*)(Bs + bb + ni * 16 * 64 + ck);
#pragma unroll
      for (int mi = 0; mi < MI; ++mi) af[mi] = *(const s16x8*)(As + ab + mi * 16 * 64 + ck);
      __builtin_amdgcn_s_setprio(1);
#pragma unroll
      for (int mi = 0; mi < MI; ++mi)
#pragma unroll
        for (int ni = 0; ni < 4; ++ni)
          acc[mi][ni] = mfma16(af[mi], bf4[ni], acc[mi][ni]);
      __builtin_amdgcn_s_setprio(0);
    }
    __builtin_amdgcn_sched_barrier(0);
    __builtin_amdgcn_s_barrier();     // all waves done reading buf (ds data already retired pre-MFMA)
    __builtin_amdgcn_sched_barrier(0);
    if (t + 2 < NT) STAGE_(buf, t + 2);
    VMCNT_L_();                       // tile t+1 landed; t+2's loads stay in flight (T4)
    __builtin_amdgcn_sched_barrier(0);
    __builtin_amdgcn_s_barrier();
    __builtin_amdgcn_sched_barrier(0);
  }
#undef STAGE_
#undef VMCNT_L_
  const int rl = khi * 4;
#pragma unroll
  for (int mi = 0; mi < MI; ++mi)
#pragma unroll
    for (int ni = 0; ni < 4; ++ni) {
      int col = n0 + wc * 64 + ni * 16 + cl;
#pragma unroll
      for (int r = 0; r < 4; ++r) {
        int rw = m0 + wr * (BM / 2) + mi * 16 + rl + r;
        if (OUT_F32) ((float*)Cp)[(size_t)rw * N + col] = acc[mi][ni][r];
        else         ((u16*)Cp)[(size_t)rw * N + col]   = f2bf(acc[mi][ni][r]);
      }
    }
}

// ---------------- RoPE + scatter (Q pre-scaled by SCALE*log2e for exp2-domain softmax) ----------------
__global__ __launch_bounds__(256) void k_rope(const u16* __restrict__ qkv, const float* __restrict__ cosT,
                                              const float* __restrict__ sinT, const int* __restrict__ sp,
                                              u16* __restrict__ qr, u16* __restrict__ kb,
                                              float* __restrict__ k_all, float* __restrict__ v_all) {
  int bt = blockIdx.x;
  int b = bt >> 9, t = bt & 511;
  int pos = sp[b] + t;
  const u16* row = qkv + (size_t)bt * NQKV;
  for (int idx = threadIdx.x; idx < 2560; idx += 256) {   // 40 roped heads * 64 pairs
    int head = idx >> 6, d = idx & 63;
    float c = cosT[pos * HD_ + d], s = sinT[pos * HD_ + d];
    float x1 = bf2f(row[head * HD_ + d]);
    float x2 = bf2f(row[head * HD_ + d + 64]);
    float y1 = x1 * c - x2 * s;
    float y2 = x2 * c + x1 * s;
    if (head < 32) {
      size_t o = (((size_t)b * H_ + head) * T_ + t) * HD_ + d;
      qr[o] = f2bf(y1 * QSC); qr[o + 64] = f2bf(y2 * QSC);
    } else {
      int g = head - 32;
      size_t o = (((size_t)b * G_ + g) * S_ + CACHE_ + t) * HD_ + d;
      kb[o] = f2bf(y1); kb[o + 64] = f2bf(y2);
      k_all[o] = y1; k_all[o + 64] = y2;
    }
  }
  for (int idx = threadIdx.x; idx < 1024; idx += 256) {   // v passthrough (f32 copy only)
    int g = idx >> 7;
    float v = bf2f(row[5120 + idx]);
    size_t o = (((size_t)b * G_ + g) * S_ + CACHE_ + t) * HD_ + (idx & 127);
    v_all[o] = v;
  }
}

// ---------------- transpose new-V slice into v_t[bg][hd][CACHE_..S] ----------------
__global__ __launch_bounds__(256) void k_tv_new(const u16* __restrict__ qkv, u16* __restrict__ vt) {
  __shared__ u16 tile[64][72];
  int bg = blockIdx.y;
  int b = bg >> 3, g = bg & 7;
  int tt = blockIdx.x >> 1, ht = blockIdx.x & 1;
  int t0 = tt * 64, hd0 = ht * 64;
  int t = threadIdx.x;
  int rr = t >> 3, c8 = (t & 7) * 8;
#pragma unroll
  for (int p = 0; p < 2; ++p) {
    int r = p * 32 + rr;
    *(u16x8*)(&tile[r][c8]) =
      *(const u16x8*)(qkv + (size_t)(b * T_ + t0 + r) * NQKV + 5120 + g * HD_ + hd0 + c8);
  }
  __syncthreads();
  int hr = t >> 4, s4 = (t & 15) * 4;
#pragma unroll
  for (int p = 0; p < 4; ++p) {
    int hd = p * 16 + hr;
    u16x4 o = { tile[s4][hd], tile[s4 + 1][hd], tile[s4 + 2][hd], tile[s4 + 3][hd] };
    *(u16x4*)(vt + ((size_t)bg * HD_ + hd0 + hd) * S_ + CACHE_ + t0 + s4) = o;
  }
}

// ---------------- flash attention, swapped-QK 32x32 structure ----------------
__global__ __launch_bounds__(512, 2) void k_attn(const u16* __restrict__ Q, const u16* __restrict__ Kc,
                                                 const u16* __restrict__ Vt, const int* __restrict__ sp,
                                                 u16* __restrict__ ctx) {
  __shared__ u16 Ks[64 * 128];   // [kv64][128 u16], row 256B, swizzle ^((row&15)<<3) in u16 units
  __shared__ u16 Vs[128 * 64];   // [hd128][64 u16], row 128B, swizzle ^((row&7)<<3)
  const int qh = blockIdx.x, h = blockIdx.y, b = blockIdx.z;
  const int g = h >> 2;
  const int tid = threadIdx.x, w = tid >> 6, lane = tid & 63;
  const int l31 = lane & 31, hh = lane >> 5;
  const int cache = sp[b];
  const int qbase = qh * 256;
  const int qtok = qbase + w * 32 + l31;     // this lane's softmax q-row (token idx)
  const size_t kvoff = (size_t)(b * G_ + g) * S_ * HD_;
  const u16* kp = Kc + kvoff;
  const u16* vp = Vt + kvoff;
  s16x8 qreg[8];
  {
    const u16* qb = Q + ((size_t)(b * H_ + h) * T_ + qtok) * HD_;
#pragma unroll
    for (int s = 0; s < 8; ++s) qreg[s] = *(const s16x8*)(qb + s * 16 + hh * 8);
  }
  f32x16 acc[4] = {};
  float mr = -1e30f, ls = 0.f;
  const int krow = w * 8 + (lane >> 3), kch = lane & 7;   // K staging: 8 rows/wave, 2x16B per lane
  const int vrow = w * 16 + (lane >> 2), vch = lane & 3;  // V staging: 16 rows/wave, 2x16B per lane
  const int kswz = (krow & 15) << 3;
  const int vswz = (vrow & 7) << 3;
  const int rdswzK = (l31 & 15) << 3;
  const int rdswzV = (l31 & 7) << 3;
  const int jm = (cache + qbase + w * 32) >> 6;           // first tile needing mask (per wave)
  const int jlastB = (cache + qbase + 255) >> 6;          // block-uniform loop bound
  const int kvlim = cache + qtok;
  // prologue: tile 0 into regs
  u16x8 rk0 = *(const u16x8*)(kp + (size_t)krow * HD_ + kch * 8);
  u16x8 rk1 = *(const u16x8*)(kp + (size_t)krow * HD_ + (kch + 8) * 8);
  u16x8 rv0 = *(const u16x8*)(vp + (size_t)vrow * S_ + vch * 8);
  u16x8 rv1 = *(const u16x8*)(vp + (size_t)vrow * S_ + (vch + 4) * 8);
  for (int j = 0; j <= jlastB; ++j) {
    __syncthreads();   // prev tile reads done; prefetch vmcnt drains here (data needed now)
    *(u16x8*)(Ks + krow * 128 + ((kch * 8) ^ kswz))        = rk0;
    *(u16x8*)(Ks + krow * 128 + (((kch + 8) * 8) ^ kswz))  = rk1;
    *(u16x8*)(Vs + vrow * 64 + ((vch * 8) ^ vswz))         = rv0;
    *(u16x8*)(Vs + vrow * 64 + (((vch + 4) * 8) ^ vswz))   = rv1;
    __syncthreads();
    if (j < jlastB) {  // prefetch next tile; in flight across whole compute phase
      rk0 = *(const u16x8*)(kp + (size_t)((j + 1) * 64 + krow) * HD_ + kch * 8);
      rk1 = *(const u16x8*)(kp + (size_t)((j + 1) * 64 + krow) * HD_ + (kch + 8) * 8);
      rv0 = *(const u16x8*)(vp + (size_t)vrow * S_ + (j + 1) * 64 + vch * 8);
      rv1 = *(const u16x8*)(vp + (size_t)vrow * S_ + (j + 1) * 64 + vch * 8 + 32);
    }
    // S^T[kv][q] = K-tile @ Q^T  (2 kv-blocks of 32)
    f32x16 sa[2] = {};
#pragma unroll
    for (int s = 0; s < 8; ++s) {
      s16x8 ka = *(const s16x8*)(Ks + l31 * 128 + ((s * 16 + hh * 8) ^ rdswzK));
      sa[0] = __builtin_amdgcn_mfma_f32_32x32x16_bf16(ka, qreg[s], sa[0], 0, 0, 0);
    }
#pragma unroll
    for (int s = 0; s < 8; ++s) {
      s16x8 ka = *(const s16x8*)(Ks + (32 + l31) * 128 + ((s * 16 + hh * 8) ^ rdswzK));
      sa[1] = __builtin_amdgcn_mfma_f32_32x32x16_bf16(ka, qreg[s], sa[1], 0, 0, 0);
    }
    // causal mask (only tiles >= jm can have masked kv)
    if (j >= jm) {
#pragma unroll
      for (int r = 0; r < 16; ++r) {
        int kv = j * 64 + (r & 3) + 8 * (r >> 2) + 4 * hh;
        if (kv > kvlim)      sa[0][r] = -1e30f;
        if (kv + 32 > kvlim) sa[1][r] = -1e30f;
      }
    }
    // row max: in-register tree + one lane-half exchange
    float mx = sa[0][0];
#pragma unroll
    for (int r = 1; r < 16; ++r) mx = fmaxf(mx, sa[0][r]);
#pragma unroll
    for (int r = 0; r < 16; ++r) mx = fmaxf(mx, sa[1][r]);
    mx = fmaxf(mx, __shfl_xor(mx, 32));
    // defer-max (T13): rescale only when max grew > 8 (exp2 domain)
    if (__any(mx > mr + 8.f)) {
      float nm = fmaxf(mr, mx);
      float al = __builtin_amdgcn_exp2f(mr - nm);
      mr = nm; ls *= al;
#pragma unroll
      for (int r = 0; r < 16; ++r) {
        float ar = __shfl(al, (r & 3) + 8 * (r >> 2) + 4 * hh, 64);
        acc[0][r] *= ar; acc[1][r] *= ar; acc[2][r] *= ar; acc[3][r] *= ar;
      }
    }
    // exp2 + row sum (in-register)
    float rs = 0.f;
#pragma unroll
    for (int r = 0; r < 16; ++r) { sa[0][r] = __builtin_amdgcn_exp2f(sa[0][r] - mr); rs += sa[0][r]; }
#pragma unroll
    for (int r = 0; r < 16; ++r) { sa[1][r] = __builtin_amdgcn_exp2f(sa[1][r] - mr); rs += sa[1][r]; }
    rs += __shfl_xor(rs, 32);
    ls += rs;
    // pack P (D-layout) into 4 MFMA A-frags, in-register (T12 pattern)
    s16x8 pf[4];
#pragma unroll
    for (int sb = 0; sb < 2; ++sb) {
      u32 a0 = pkbf(sa[sb][0],  sa[sb][1]),  a1 = pkbf(sa[sb][2],  sa[sb][3]);
      u32 b0 = pkbf(sa[sb][4],  sa[sb][5]),  b1 = pkbf(sa[sb][6],  sa[sb][7]);
      u32 c0 = pkbf(sa[sb][8],  sa[sb][9]),  c1 = pkbf(sa[sb][10], sa[sb][11]);
      u32 d0 = pkbf(sa[sb][12], sa[sb][13]), d1 = pkbf(sa[sb][14], sa[sb][15]);
      u32 xa0 = __shfl_xor(a0, 32), xa1 = __shfl_xor(a1, 32);
      u32 xb0 = __shfl_xor(b0, 32), xb1 = __shfl_xor(b1, 32);
      u32 xc0 = __shfl_xor(c0, 32), xc1 = __shfl_xor(c1, 32);
      u32 xd0 = __shfl_xor(d0, 32), xd1 = __shfl_xor(d1, 32);
      u32x4 f0 = { hh ? xb0 : a0, hh ? xb1 : a1, hh ? b0 : xa0, hh ? b1 : xa1 };
      u32x4 f1 = { hh ? xd0 : c0, hh ? xd1 : c1, hh ? d0 : xc0, hh ? d1 : xc1 };
      pf[sb * 2]     = __builtin_bit_cast(s16x8, f0);
      pf[sb * 2 + 1] = __builtin_bit_cast(s16x8, f1);
    }
    // O += P V  (B-frags straight from swizzled Vs)
#pragma unroll
    for (int hb = 0; hb < 4; ++hb) {
      const int vro = hb * 32 + l31;
#pragma unroll
      for (int kb = 0; kb < 4; ++kb) {
        s16x8 vb = *(const s16x8*)(Vs + vro * 64 + ((kb * 16 + hh * 8) ^ rdswzV));
        acc[hb] = __builtin_amdgcn_mfma_f32_32x32x16_bf16(pf[kb], vb, acc[hb], 0, 0, 0);
      }
    }
  }
  // epilogue: normalize rows (ls lives at lane l31==row) and store ctx
  float inv = 1.0f / ls;
#pragma unroll
  for (int r = 0; r < 16; ++r) {
    int ql = (r & 3) + 8 * (r >> 2) + 4 * hh;
    float ivr = __shfl(inv, ql, 64);
    u16* cb = ctx + ((size_t)(b * T_ + qbase + w * 32 + ql)) * 4096 + h * HD_ + l31;
    cb[0]  = f2bf(acc[0][r] * ivr);
    cb[32] = f2bf(acc[1][r] * ivr);
    cb[64] = f2bf(acc[2][r] * ivr);
    cb[96] = f2bf(acc[3][r] * ivr);
  }
}

// ---------------- launch ----------------
extern "C" void kernel_launch(void* const* d_in, const int* in_sizes, int n_in,
                              void* d_out, int out_size, void* d_ws, size_t ws_size,
                              hipStream_t stream) {
  const float* x      = (const float*)d_in[0];
  // d_in[1] = mask (derived analytically; unused)
  const float* cosT   = (const float*)d_in[2];
  const float* sinT   = (const float*)d_in[3];
  const int*   sp     = (const int*)d_in[4];
  const float* prev_k = (const float*)d_in[5];
  const float* prev_v = (const float*)d_in[6];
  const float* q_w    = (const float*)d_in[7];
  const float* k_w    = (const float*)d_in[8];
  const float* v_w    = (const float*)d_in[9];
  const float* o_w    = (const float*)d_in[10];

  float* out   = (float*)d_out;
  float* k_all = out + (size_t)B_ * T_ * H_ * HD_;      // +8388608
  float* v_all = k_all + (size_t)B_ * G_ * S_ * HD_;    // +16777216

  char* w = (char*)d_ws;
  u16* wt_qkv = (u16*)(w);                 // [6144][4096] bf16   50331648 B
  u16* wt_o   = (u16*)(w + 50331648);      // [4096][4096] bf16   33554432 B
  u16* x_bf   = (u16*)(w + 83886080);      // [2048][4096] bf16   16777216 B
  u16* qkv_bf = (u16*)(w + 100663296);     // [2048][6144] bf16   25165824 B
  u16* q_rope = (u16*)(w + 125829120);     // [4][32][512][128]   16777216 B
  u16* k_bf   = (u16*)(w + 142606336);     // [4][8][4096][128]   33554432 B
  u16* v_t    = (u16*)(w + 176160768);     // [4][8][128][4096]   33554432 B
  u16* ctx    = (u16*)(w + 209715200);     // [2048][4096]        16777216 B
  if (ws_size < 226492416ull) return;      // workspace too small -> bench will flag it

  k_cvt_x<<<8192, 256, 0, stream>>>(x, x_bf);
  k_twt<<<dim3(64, 64), 256, 0, stream>>>(q_w, 4096, wt_qkv);
  k_twt<<<dim3(64, 16), 256, 0, stream>>>(k_w, 1024, wt_qkv + (size_t)4096 * 4096);
  k_twt<<<dim3(64, 16), 256, 0, stream>>>(v_w, 1024, wt_qkv + (size_t)5120 * 4096);
  k_twt<<<dim3(64, 64), 256, 0, stream>>>(o_w, 4096, wt_o);
  k_prep_k<<<dim3(448, 32), 256, 0, stream>>>(prev_k, k_all, k_bf);
  k_prep_v<<<dim3(56, 32), 256, 0, stream>>>(prev_v, v_all, v_t);
  k_gemm2<256, false><<<192, 512, 0, stream>>>(x_bf, wt_qkv, qkv_bf, M_, NQKV, 4096);
  k_rope<<<2048, 256, 0, stream>>>(qkv_bf, cosT, sinT, sp, q_rope, k_bf, k_all, v_all);
  k_tv_new<<<dim3(16, 32), 256, 0, stream>>>(qkv_bf, v_t);
  k_attn<<<dim3(2, 32, 4), 512, 0, stream>>>(q_rope, k_bf, v_t, sp, ctx);
  k_gemm2<128, true><<<256, 512, 0, stream>>>(ctx, wt_o, out, M_, 4096, 4096);
}